// Round 1
// baseline (417.650 us; speedup 1.0000x reference)
//
#include <hip/hip_runtime.h>

#define BLOCK 256
#define GRID_CAP 8192

// Native vector type so clang's nontemporal builtins accept it
typedef float f32x4 __attribute__((ext_vector_type(4)));

// out = gelu(x), tanh approximation:
//   gelu(x) = x * (1 - 1/(exp(2*0.7978845608*(x + 0.044715 x^3)) + 1))
//   exp(2z) = 2^(z * 2.8853900818);  z = 0.7978845608 * x * (1 + 0.044715 x^2)
//   => arg = (0.7978845608 * 2.8853900818) * x * (1 + 0.044715 x^2)
__device__ __forceinline__ float gelu_fast(float x) {
    float x2 = x * x;
    float p  = fmaf(0.044715f, x2, 1.0f);
    float a  = 2.302160895f * x;          // 0.7978845608 * 2.8853900818
    float e  = __builtin_amdgcn_exp2f(a * p);
    float r  = __builtin_amdgcn_rcpf(e + 1.0f);
    return fmaf(-x, r, x);                // x * (1 - r)
}

__device__ __forceinline__ f32x4 gelu4(f32x4 v) {
    f32x4 r;
    r.x = gelu_fast(v.x);
    r.y = gelu_fast(v.y);
    r.z = gelu_fast(v.z);
    r.w = gelu_fast(v.w);
    return r;
}

// Grid-stride, 2 x float4 per thread per iteration (both loads in flight
// before compute), nontemporal since there is zero reuse and the working
// set (512 MiB) exceeds the 256 MiB L3.
__global__ __launch_bounds__(BLOCK) void secgelu_kernel(
        const f32x4* __restrict__ x4,
        f32x4* __restrict__ o4,
        long long n4) {
    const long long chunk   = (long long)BLOCK * 2;
    const long long gstride = (long long)gridDim.x * chunk;

    for (long long base = (long long)blockIdx.x * chunk; base < n4; base += gstride) {
        long long i0 = base + threadIdx.x;
        long long i1 = i0 + BLOCK;
        bool h0 = i0 < n4;
        bool h1 = i1 < n4;
        f32x4 v0, v1;
        if (h0) v0 = __builtin_nontemporal_load(&x4[i0]);
        if (h1) v1 = __builtin_nontemporal_load(&x4[i1]);
        if (h0) { f32x4 r0 = gelu4(v0); __builtin_nontemporal_store(r0, &o4[i0]); }
        if (h1) { f32x4 r1 = gelu4(v1); __builtin_nontemporal_store(r1, &o4[i1]); }
    }
}

// Scalar tail for n % 4 != 0 (not hit at the bench shape, kept for safety)
__global__ void secgelu_tail(const float* __restrict__ x,
                             float* __restrict__ out,
                             long long start, long long n) {
    long long i = start + (long long)blockIdx.x * blockDim.x + threadIdx.x;
    if (i < n) out[i] = gelu_fast(x[i]);
}

extern "C" void kernel_launch(void* const* d_in, const int* in_sizes, int n_in,
                              void* d_out, int out_size, void* d_ws, size_t ws_size,
                              hipStream_t stream) {
    const float* x = (const float*)d_in[0];
    float* out = (float*)d_out;
    long long n = (long long)in_sizes[0];
    long long n4 = n >> 2;

    if (n4 > 0) {
        const long long chunk = (long long)BLOCK * 2;
        long long blocks = (n4 + chunk - 1) / chunk;
        if (blocks > GRID_CAP) blocks = GRID_CAP;
        secgelu_kernel<<<(dim3)(unsigned)blocks, BLOCK, 0, stream>>>(
            (const f32x4*)x, (f32x4*)out, n4);
    }
    long long tail = n - (n4 << 2);
    if (tail > 0) {
        secgelu_tail<<<1, 64, 0, stream>>>(x, out, n4 << 2, n);
    }
}